// Round 3
// baseline (455.699 us; speedup 1.0000x reference)
//
#include <hip/hip_runtime.h>
#include <math.h>

#define NPARTS 1024
#define BLOCK 256
#define WPB (BLOCK / 64)          // waves per block
#define T 4                       // tiles (16 atoms each) per wave per iteration
#define GRID_BLOCKS 2048          // grid-stride cap (memory-bound guideline)

typedef __attribute__((ext_vector_type(4))) _Float16 half4;
typedef __attribute__((ext_vector_type(4))) float floatx4;   // clang vector: ok for nontemporal builtins

// Transposed-chain MFMA MLP (round-1 structure, verified):
//   layer L computes out^T = W_L * h^T via v_mfma_f32_16x16x16_f16.
//   A-frag = W_L[lane%16][4*(lane/16)+i]  (wave-uniform), C-init = bias.
//   C/D layout == next layer's B layout, so inter-layer = ELU+cvt in regs.
// Round-2 change: 4-tile unroll per wave iteration. All four 1 KB x-loads
// (4 KB contiguous per wave) + part loads issue BEFORE any compute ->
// 4x memory-level parallelism per wave. Round-1 version had exactly one
// outstanding load per wave (latency-bound at ~4.2 TB/s vs 6.3 achievable).
// Round-3 fix: nontemporal store must use a clang ext_vector type, not
// HIP_vector_type float4 (compile error on gfx950).
__global__ __launch_bounds__(BLOCK, 6) void nodes_mlp_mfma(
    const float* __restrict__ x,       // [N,16]
    const float* __restrict__ charge,  // [1024]
    const float* __restrict__ W1, const float* __restrict__ b1,
    const float* __restrict__ W2, const float* __restrict__ b2,
    const float* __restrict__ W3, const float* __restrict__ b3,
    const int*   __restrict__ part,    // [N]
    float* __restrict__ out,           // [N,16]
    int n)
{
    __shared__ float sq[NPARTS];
    for (int i = threadIdx.x; i < NPARTS; i += BLOCK) sq[i] = charge[i];
    __syncthreads();

    const int lane = threadIdx.x & 63;
    const int col  = lane & 15;   // atom-in-tile (B/D column); W row j for A-frag
    const int g    = lane >> 4;   // k-group: frags hold k/rows 4g..4g+3

    // ---- wave-uniform fragments: A = W_L, C-init = bias (D = A*B + C) ----
    half4  aW[3];
    floatx4 cB[3];
    {
        const float* Ws[3] = {W1, W2, W3};
        const float* bs[3] = {b1, b2, b3};
#pragma unroll
        for (int L = 0; L < 3; ++L) {
            const float4 wv = *(const float4*)(Ws[L] + col * 16 + 4 * g);
            half4 a;
            a[0] = (_Float16)wv.x; a[1] = (_Float16)wv.y;
            a[2] = (_Float16)wv.z; a[3] = (_Float16)wv.w;
            aW[L] = a;
            const float4 bv = *(const float4*)(bs[L] + 4 * g);
            floatx4 c;
            c[0] = bv.x; c[1] = bv.y; c[2] = bv.z; c[3] = bv.w;
            cB[L] = c;
        }
    }

    const int ntiles = (n + 15) >> 4;
    const int nwaves = gridDim.x * WPB;
    const int wid    = blockIdx.x * WPB + (threadIdx.x >> 6);

    for (int t0 = wid * T; t0 < ntiles; t0 += nwaves * T) {

        // ---- phase 1: issue ALL loads (4 KB x contiguous per wave + part) ----
        floatx4 xv[T];
        int     pp[T];
        int     rw[T];
#pragma unroll
        for (int u = 0; u < T; ++u) {
            const int tile = t0 + u;
            const int row  = tile * 16 + col;
            const int rowc = (row < n) ? row : (n - 1);
            rw[u] = row;
            xv[u] = *(const floatx4*)(x + rowc * 16 + 4 * g);
            pp[u] = part[rowc];
        }

        // ---- phase 2: four independent MLP chains, then store ----
#pragma unroll
        for (int u = 0; u < T; ++u) {
            half4 bx;
            bx[0] = (_Float16)xv[u][0]; bx[1] = (_Float16)xv[u][1];
            bx[2] = (_Float16)xv[u][2]; bx[3] = (_Float16)xv[u][3];

            floatx4 d = __builtin_amdgcn_mfma_f32_16x16x16f16(aW[0], bx, cB[0], 0, 0, 0);

            half4 h2;
#pragma unroll
            for (int i = 0; i < 4; ++i) {
                float v = d[i];
                v = (v > 0.0f) ? v : (__expf(v) - 1.0f);
                h2[i] = (_Float16)v;
            }
            d = __builtin_amdgcn_mfma_f32_16x16x16f16(aW[1], h2, cB[1], 0, 0, 0);

            half4 h3;
#pragma unroll
            for (int i = 0; i < 4; ++i) {
                float v = d[i];
                v = (v > 0.0f) ? v : (__expf(v) - 1.0f);
                h3[i] = (_Float16)v;
            }
            d = __builtin_amdgcn_mfma_f32_16x16x16f16(aW[2], h3, cB[2], 0, 0, 0);

            const int   p   = pp[u];
            const float add = (float)p + sq[p];

            floatx4 r;
            {
                float v0 = d[0]; v0 = (v0 > 0.0f) ? v0 : (__expf(v0) - 1.0f);
                float v1 = d[1]; v1 = (v1 > 0.0f) ? v1 : (__expf(v1) - 1.0f);
                float v2 = d[2]; v2 = (v2 > 0.0f) ? v2 : (__expf(v2) - 1.0f);
                float v3 = d[3]; v3 = (v3 > 0.0f) ? v3 : (__expf(v3) - 1.0f);
                r[0] = v0 + add; r[1] = v1 + add; r[2] = v2 + add; r[3] = v3 + add;
            }

            if (rw[u] < n) {
                __builtin_nontemporal_store(r, (floatx4*)(out + rw[u] * 16 + 4 * g));
            }
        }
    }
}

extern "C" void kernel_launch(void* const* d_in, const int* in_sizes, int n_in,
                              void* d_out, int out_size, void* d_ws, size_t ws_size,
                              hipStream_t stream) {
    const float* x      = (const float*)d_in[0];
    const float* charge = (const float*)d_in[1];
    const float* W1     = (const float*)d_in[2];
    const float* b1     = (const float*)d_in[3];
    const float* W2     = (const float*)d_in[4];
    const float* b2     = (const float*)d_in[5];
    const float* W3     = (const float*)d_in[6];
    const float* b3     = (const float*)d_in[7];
    const int*   part   = (const int*)d_in[8];
    float* out = (float*)d_out;

    const int n      = in_sizes[8];
    const int ntiles = (n + 15) >> 4;
    int grid = (ntiles + WPB * T - 1) / (WPB * T);
    if (grid > GRID_BLOCKS) grid = GRID_BLOCKS;

    nodes_mlp_mfma<<<grid, BLOCK, 0, stream>>>(
        x, charge, W1, b1, W2, b2, W3, b3, part, out, n);
}

// Round 5
// 455.122 us; speedup vs baseline: 1.0013x; 1.0013x over previous
//
#include <hip/hip_runtime.h>
#include <math.h>

#define NPARTS 1024
#define BLOCK 256
#define WPB (BLOCK / 64)          // waves per block
#define T 2                       // tiles (16 atoms) per wave per pipeline stage
#define GRID_BLOCKS 2048          // grid-stride cap (memory-bound guideline)

typedef __attribute__((ext_vector_type(4))) _Float16 half4;
typedef __attribute__((ext_vector_type(4))) float floatx4;

// Transposed-chain MFMA MLP (verified rounds 1/3):
//   layer L computes out^T = W_L * h^T via v_mfma_f32_16x16x16_f16.
//   A-frag = W_L[lane%16][4*(lane/16)+i] (wave-uniform), C-init = bias.
//   C/D layout == next layer's B layout -> inter-layer = ELU+cvt in regs.
// Round-4/5: round-3's phase-split batch was DELETED by the scheduler
// (VGPR=28 proved the 4 loads were re-sunk -> 1 outstanding load, latency-
// bound at 2.5 TB/s). Now: double-buffered software pipeline — prefetch
// group t+stride BEFORE computing group t. The prefetched value is live
// across the whole compute phase, so it cannot be sunk; sched_barrier(0)
// pins issue order. Loads unconditional (clamped tile; tail recompute is
// idempotent) to keep one basic block. Round-5 fix: plain (_Float16)
// casts, not cvt_pkrtz builtin (__fp16 vs _Float16 vector type clash).
__global__ __launch_bounds__(BLOCK, 8) void nodes_mlp_mfma(
    const float* __restrict__ x,       // [N,16]
    const float* __restrict__ charge,  // [1024]
    const float* __restrict__ W1, const float* __restrict__ b1,
    const float* __restrict__ W2, const float* __restrict__ b2,
    const float* __restrict__ W3, const float* __restrict__ b3,
    const int*   __restrict__ part,    // [N]
    float* __restrict__ out,           // [N,16]
    int n)
{
    __shared__ float sq[NPARTS];
    for (int i = threadIdx.x; i < NPARTS; i += BLOCK) sq[i] = charge[i];
    __syncthreads();

    const int lane = threadIdx.x & 63;
    const int col  = lane & 15;   // atom-in-tile (B/D column); W row j for A-frag
    const int g    = lane >> 4;   // k-group: frags hold k/rows 4g..4g+3

    // ---- wave-uniform fragments: A = W_L, C-init = bias (D = A*B + C) ----
    half4  aW[3];
    floatx4 cB[3];
    {
        const float* Ws[3] = {W1, W2, W3};
        const float* bs[3] = {b1, b2, b3};
#pragma unroll
        for (int L = 0; L < 3; ++L) {
            const float4 wv = *(const float4*)(Ws[L] + col * 16 + 4 * g);
            half4 a;
            a[0] = (_Float16)wv.x; a[1] = (_Float16)wv.y;
            a[2] = (_Float16)wv.z; a[3] = (_Float16)wv.w;
            aW[L] = a;
            const float4 bv = *(const float4*)(bs[L] + 4 * g);
            floatx4 c;
            c[0] = bv.x; c[1] = bv.y; c[2] = bv.z; c[3] = bv.w;
            cB[L] = c;
        }
    }

    const int ntiles = (n + 15) >> 4;
    const int nwaves = gridDim.x * WPB;
    const int wid    = blockIdx.x * WPB + (threadIdx.x >> 6);
    const int stride = nwaves * T;

    int t0 = wid * T;
    if (t0 >= ntiles) return;

    // ---- prologue: load group t0 ----
    floatx4 xc[T];
    int     pc[T];
#pragma unroll
    for (int u = 0; u < T; ++u) {
        int tt   = t0 + u; if (tt > ntiles - 1) tt = ntiles - 1;
        int row  = tt * 16 + col;
        int rowc = (row < n) ? row : (n - 1);
        xc[u] = *(const floatx4*)(x + rowc * 16 + 4 * g);
        pc[u] = part[rowc];
    }

    for (; t0 < ntiles; t0 += stride) {
        // ---- prefetch group t0+stride (clamped, unconditional) ----
        floatx4 xn[T];
        int     pn[T];
#pragma unroll
        for (int u = 0; u < T; ++u) {
            int tt   = t0 + stride + u; if (tt > ntiles - 1) tt = ntiles - 1;
            int row  = tt * 16 + col;
            int rowc = (row < n) ? row : (n - 1);
            xn[u] = *(const floatx4*)(x + rowc * 16 + 4 * g);
            pn[u] = part[rowc];
        }
        __builtin_amdgcn_sched_barrier(0);   // pin: prefetch issues before compute

        // ---- compute + store group t0 from the current buffer ----
#pragma unroll
        for (int u = 0; u < T; ++u) {
            int tt  = t0 + u; if (tt > ntiles - 1) tt = ntiles - 1;
            int row = tt * 16 + col;

            half4 bx;
            bx[0] = (_Float16)xc[u][0]; bx[1] = (_Float16)xc[u][1];
            bx[2] = (_Float16)xc[u][2]; bx[3] = (_Float16)xc[u][3];

            floatx4 d = __builtin_amdgcn_mfma_f32_16x16x16f16(aW[0], bx, cB[0], 0, 0, 0);

            half4 h2;
#pragma unroll
            for (int i = 0; i < 4; ++i) {
                float v = d[i];
                v = (v > 0.0f) ? v : (__expf(v) - 1.0f);
                h2[i] = (_Float16)v;
            }
            d = __builtin_amdgcn_mfma_f32_16x16x16f16(aW[1], h2, cB[1], 0, 0, 0);

            half4 h3;
#pragma unroll
            for (int i = 0; i < 4; ++i) {
                float v = d[i];
                v = (v > 0.0f) ? v : (__expf(v) - 1.0f);
                h3[i] = (_Float16)v;
            }
            d = __builtin_amdgcn_mfma_f32_16x16x16f16(aW[2], h3, cB[2], 0, 0, 0);

            const int   p   = pc[u];
            const float add = (float)p + sq[p];

            floatx4 r;
            {
                float v0 = d[0]; v0 = (v0 > 0.0f) ? v0 : (__expf(v0) - 1.0f);
                float v1 = d[1]; v1 = (v1 > 0.0f) ? v1 : (__expf(v1) - 1.0f);
                float v2 = d[2]; v2 = (v2 > 0.0f) ? v2 : (__expf(v2) - 1.0f);
                float v3 = d[3]; v3 = (v3 > 0.0f) ? v3 : (__expf(v3) - 1.0f);
                r[0] = v0 + add; r[1] = v1 + add; r[2] = v2 + add; r[3] = v3 + add;
            }

            if (row < n) {
                __builtin_nontemporal_store(r, (floatx4*)(out + row * 16 + 4 * g));
            }
        }

        // ---- rotate buffers ----
#pragma unroll
        for (int u = 0; u < T; ++u) { xc[u] = xn[u]; pc[u] = pn[u]; }
    }
}

extern "C" void kernel_launch(void* const* d_in, const int* in_sizes, int n_in,
                              void* d_out, int out_size, void* d_ws, size_t ws_size,
                              hipStream_t stream) {
    const float* x      = (const float*)d_in[0];
    const float* charge = (const float*)d_in[1];
    const float* W1     = (const float*)d_in[2];
    const float* b1     = (const float*)d_in[3];
    const float* W2     = (const float*)d_in[4];
    const float* b2     = (const float*)d_in[5];
    const float* W3     = (const float*)d_in[6];
    const float* b3     = (const float*)d_in[7];
    const int*   part   = (const int*)d_in[8];
    float* out = (float*)d_out;

    const int n      = in_sizes[8];
    const int ntiles = (n + 15) >> 4;
    int grid = (ntiles + WPB * T - 1) / (WPB * T);
    if (grid > GRID_BLOCKS) grid = GRID_BLOCKS;

    nodes_mlp_mfma<<<grid, BLOCK, 0, stream>>>(
        x, charge, W1, b1, W2, b2, W3, b3, part, out, n);
}